// Round 3
// baseline (492.437 us; speedup 1.0000x reference)
//
#include <hip/hip_runtime.h>

#define IMG_H 4096
#define IMG_W 4096
#define RAD 4
#define TSX 32
#define TSY 64
#define LROWS (TSY + 2*RAD)   // 72
#define LCOLS (TSX + 2*RAD)   // 40
#define LSTRIDE 44            // row stride in floats -> 176B, 16B-aligned rows

typedef float f32x2 __attribute__((ext_vector_type(2)));

__device__ __forceinline__ int reflect_idx(int i, int n) {
    i = (i < 0) ? -i : i;
    i = (i >= n) ? (2 * n - 2 - i) : i;
    return i;
}

__device__ __forceinline__ constexpr int sc_slot(int d2) {
    switch (d2) {
        case 0: return 0;  case 1: return 1;  case 2: return 2;  case 4: return 3;
        case 5: return 4;  case 8: return 5;  case 9: return 6;  case 10: return 7;
        case 13: return 8; case 16: return 9; case 17: return 10; case 18: return 11;
        case 20: return 12; case 25: return 13; case 32: return 14;
    }
    return 0;
}

// Packed (v2f32) bilateral tap row: compiler selects v_pk_{add,mul,fma}_f32
// on gfx950 for these vector ops (LLVM packed-fp32 ISel, gfx90a+).
__device__ __forceinline__ void proc_row(const f32x2* rp, const f32x2* sh,
                                         const f32x2 cA, const f32x2 cB,
                                         const f32x2* sc2v, int dyy,
                                         f32x2& numA, f32x2& numB,
                                         f32x2& denA, f32x2& denB,
                                         const f32x2 kr2) {
#pragma unroll
    for (int dx = 0; dx < 9; ++dx) {
        const int d2 = (dx - 4) * (dx - 4) + dyy;   // compile-time after unroll
        f32x2 winA = (dx & 1) ? sh[dx >> 1] : rp[dx >> 1];
        f32x2 winB = (dx & 1) ? sh[(dx >> 1) + 1] : rp[(dx >> 1) + 1];
        f32x2 scp = sc2v[sc_slot(d2)];

        f32x2 dA = winA - cA;
        f32x2 aA = __builtin_elementwise_fma(dA * kr2, dA, scp);
        f32x2 wA;
        wA.x = __builtin_amdgcn_exp2f(aA.x);
        wA.y = __builtin_amdgcn_exp2f(aA.y);
        numA = __builtin_elementwise_fma(wA, winA, numA);
        denA += wA;

        f32x2 dB = winB - cB;
        f32x2 aB = __builtin_elementwise_fma(dB * kr2, dB, scp);
        f32x2 wB;
        wB.x = __builtin_amdgcn_exp2f(aB.x);
        wB.y = __builtin_amdgcn_exp2f(aB.y);
        numB = __builtin_elementwise_fma(wB, winB, numB);
        denB += wB;
    }
}

__global__ __launch_bounds__(256) void bilateral_kernel(const float* __restrict__ in,
                                                        float* __restrict__ out) {
    __shared__ float tile[LROWS][LSTRIDE];
    const int bx = blockIdx.x * TSX;
    const int by = blockIdx.y * TSY;
    const int tid = threadIdx.x;

    // Stage 72x40 input window (reflect at borders) into LDS.
    for (int i = tid; i < LROWS * LCOLS; i += 256) {
        int ly = i / LCOLS;
        int lx = i - ly * LCOLS;
        int gy = reflect_idx(by + ly - RAD, IMG_H);
        int gx = reflect_idx(bx + lx - RAD, IMG_W);
        tile[ly][lx] = in[gy * IMG_W + gx];
    }
    __syncthreads();

    // 256 threads = 8 tx (4 px wide) x 32 tyt (2 px tall) -> 32x64 outputs/block.
    const int tx = tid & 7;
    const int tyt = tid >> 3;
    const int x0 = tx * 4;

    constexpr float LOG2E = 1.4426950408889634f;
    constexpr float KR = -50.0f * LOG2E;          // -log2e/(2*0.1^2)
    constexpr float SC_COEF = -LOG2E / 18.0f;     // -log2e/(2*3^2)
    constexpr int D2V[15] = {0,1,2,4,5,8,9,10,13,16,17,18,20,25,32};

    // Broadcast spatial-log-weight constants; identity-asm pin blocks per-use remat.
    f32x2 sc2v[15];
#pragma unroll
    for (int k = 0; k < 15; ++k) {
        float s = SC_COEF * (float)D2V[k];
        sc2v[k] = f32x2{s, s};
        asm("" : "+v"(sc2v[k]));
    }
    f32x2 kr2 = f32x2{KR, KR};
    asm("" : "+v"(kr2));

    // Center values for the two pixel rows, as pairs.
    const float* c0 = &tile[2 * tyt + RAD][x0 + RAD];
    const float* c1 = &tile[2 * tyt + RAD + 1][x0 + RAD];
    float4 cv0 = *reinterpret_cast<const float4*>(c0);
    float4 cv1 = *reinterpret_cast<const float4*>(c1);
    f32x2 c0a = f32x2{cv0.x, cv0.y}, c0b = f32x2{cv0.z, cv0.w};
    f32x2 c1a = f32x2{cv1.x, cv1.y}, c1b = f32x2{cv1.z, cv1.w};

    f32x2 n0a = {0.f,0.f}, n0b = {0.f,0.f}, n1a = {0.f,0.f}, n1b = {0.f,0.f};
    f32x2 d0a = {0.f,0.f}, d0b = {0.f,0.f}, d1a = {0.f,0.f}, d1b = {0.f,0.f};

#pragma unroll
    for (int r = 0; r < 10; ++r) {
        const float* rowbase = &tile[2 * tyt + r][x0];
        float4 q0 = *reinterpret_cast<const float4*>(rowbase);
        float4 q1 = *reinterpret_cast<const float4*>(rowbase + 4);
        float4 q2 = *reinterpret_cast<const float4*>(rowbase + 8);
        f32x2 rp[6], sh[5];
        rp[0] = f32x2{q0.x, q0.y}; rp[1] = f32x2{q0.z, q0.w};
        rp[2] = f32x2{q1.x, q1.y}; rp[3] = f32x2{q1.z, q1.w};
        rp[4] = f32x2{q2.x, q2.y}; rp[5] = f32x2{q2.z, q2.w};
        sh[0] = f32x2{q0.y, q0.z}; sh[1] = f32x2{q0.w, q1.x};
        sh[2] = f32x2{q1.y, q1.z}; sh[3] = f32x2{q1.w, q2.x};
        sh[4] = f32x2{q2.y, q2.z};

        if (r <= 8) {   // pixel-row 0: dy = r
            proc_row(rp, sh, c0a, c0b, sc2v, (r - 4) * (r - 4),
                     n0a, n0b, d0a, d0b, kr2);
        }
        if (r >= 1) {   // pixel-row 1: dy = r - 1
            proc_row(rp, sh, c1a, c1b, sc2v, (r - 5) * (r - 5),
                     n1a, n1b, d1a, d1b, kr2);
        }
    }

    float4 o0, o1;
    o0.x = n0a.x / d0a.x;
    o0.y = n0a.y / d0a.y;
    o0.z = n0b.x / d0b.x;
    o0.w = n0b.y / d0b.y;
    o1.x = n1a.x / d1a.x;
    o1.y = n1a.y / d1a.y;
    o1.z = n1b.x / d1b.x;
    o1.w = n1b.y / d1b.y;

    const int orow0 = by + 2 * tyt;
    *reinterpret_cast<float4*>(&out[(size_t)orow0 * IMG_W + bx + x0]) = o0;
    *reinterpret_cast<float4*>(&out[(size_t)(orow0 + 1) * IMG_W + bx + x0]) = o1;
}

extern "C" void kernel_launch(void* const* d_in, const int* in_sizes, int n_in,
                              void* d_out, int out_size, void* d_ws, size_t ws_size,
                              hipStream_t stream) {
    const float* in = (const float*)d_in[0];
    float* out = (float*)d_out;
    dim3 grid(IMG_W / TSX, IMG_H / TSY);
    bilateral_kernel<<<grid, 256, 0, stream>>>(in, out);
}

// Round 5
// 453.855 us; speedup vs baseline: 1.0850x; 1.0850x over previous
//
#include <hip/hip_runtime.h>

#define IMG_H 4096
#define IMG_W 4096
#define RAD 4
#define TSX 64
#define TSY 32
#define LROWS (TSY + 2*RAD)   // 40
#define LCOLS (TSX + 2*RAD)   // 72
#define LSTRIDE 72            // floats; 288B rows, 16B-aligned; no pad needed
                              // (8-lane b128 groups cover 32 consecutive banks -> conflict-free)

__device__ __forceinline__ int reflect_idx(int i, int n) {
    i = (i < 0) ? -i : i;
    i = (i >= n) ? (2 * n - 2 - i) : i;
    return i;
}

__global__ __launch_bounds__(256) void bilateral_kernel(const float* __restrict__ in,
                                                        float* __restrict__ out) {
    __shared__ float tile[LROWS][LSTRIDE];
    const int bx = blockIdx.x * TSX;
    const int by = blockIdx.y * TSY;
    const int tid = threadIdx.x;

    // Stage 40x72 input window (reflect at borders) into LDS. 2880 floats.
    for (int i = tid; i < LROWS * LCOLS; i += 256) {
        int ly = i / LCOLS;
        int lx = i - ly * LCOLS;
        int gy = reflect_idx(by + ly - RAD, IMG_H);
        int gx = reflect_idx(bx + lx - RAD, IMG_W);
        tile[ly][lx] = in[gy * IMG_W + gx];
    }
    __syncthreads();

    // 256 threads = 16 tx (4 px wide) x 16 tyt (2 px tall) -> 64x32 outputs/block.
    const int tx = tid & 15;
    const int tyt = tid >> 4;
    const int x0 = tx * 4;

    constexpr float LOG2E = 1.4426950408889634f;
    constexpr float KR = -50.0f * LOG2E;          // -log2e/(2*sigma_r^2), sigma_r=0.1
    constexpr float NEG2KR = -2.0f * KR;
    constexpr float SC_COEF = -LOG2E / 18.0f;     // -log2e/(2*sigma_s^2), sigma_s=3

    // Per-pixel linear coefficient B = -2*KR*c.  (The dropped KR*c^2 term is a
    // per-pixel constant factor on w that cancels in num/den.)
    float B0[4], B1[4];
#pragma unroll
    for (int p = 0; p < 4; ++p) {
        B0[p] = NEG2KR * tile[2 * tyt + RAD][x0 + RAD + p];
        B1[p] = NEG2KR * tile[2 * tyt + RAD + 1][x0 + RAD + p];
    }

    float n0[4] = {0.f,0.f,0.f,0.f}, d0[4] = {0.f,0.f,0.f,0.f};
    float n1[4] = {0.f,0.f,0.f,0.f}, d1[4] = {0.f,0.f,0.f,0.f};

#pragma unroll
    for (int r = 0; r < 10; ++r) {
        const float* rowp = &tile[2 * tyt + r][x0];
        float4 q0 = *reinterpret_cast<const float4*>(rowp);
        float4 q1 = *reinterpret_cast<const float4*>(rowp + 4);
        float4 q2 = *reinterpret_cast<const float4*>(rowp + 8);
        float v[12] = {q0.x, q0.y, q0.z, q0.w,
                       q1.x, q1.y, q1.z, q1.w,
                       q2.x, q2.y, q2.z, q2.w};

        if (r <= 8) {   // pixel-row 0 sees this tile row as dy = r
            const int dyy = (r - 4) * (r - 4);
#pragma unroll
            for (int dx = 0; dx < 9; ++dx) {
                const float sc = SC_COEF * (float)((dx - 4) * (dx - 4) + dyy);
#pragma unroll
                for (int p = 0; p < 4; ++p) {
                    float vv = v[dx + p];
                    float t = fmaf(KR, vv, B0[p]);
                    float w = __builtin_amdgcn_exp2f(fmaf(vv, t, sc));
                    n0[p] = fmaf(w, vv, n0[p]);
                    d0[p] += w;
                }
            }
        }
        if (r >= 1) {   // pixel-row 1 sees this tile row as dy = r - 1
            const int dyy = (r - 5) * (r - 5);
#pragma unroll
            for (int dx = 0; dx < 9; ++dx) {
                const float sc = SC_COEF * (float)((dx - 4) * (dx - 4) + dyy);
#pragma unroll
                for (int p = 0; p < 4; ++p) {
                    float vv = v[dx + p];
                    float t = fmaf(KR, vv, B1[p]);
                    float w = __builtin_amdgcn_exp2f(fmaf(vv, t, sc));
                    n1[p] = fmaf(w, vv, n1[p]);
                    d1[p] += w;
                }
            }
        }
    }

    float4 o0, o1;
    o0.x = n0[0] / d0[0]; o0.y = n0[1] / d0[1];
    o0.z = n0[2] / d0[2]; o0.w = n0[3] / d0[3];
    o1.x = n1[0] / d1[0]; o1.y = n1[1] / d1[1];
    o1.z = n1[2] / d1[2]; o1.w = n1[3] / d1[3];

    const int orow0 = by + 2 * tyt;
    *reinterpret_cast<float4*>(&out[(size_t)orow0 * IMG_W + bx + x0]) = o0;
    *reinterpret_cast<float4*>(&out[(size_t)(orow0 + 1) * IMG_W + bx + x0]) = o1;
}

extern "C" void kernel_launch(void* const* d_in, const int* in_sizes, int n_in,
                              void* d_out, int out_size, void* d_ws, size_t ws_size,
                              hipStream_t stream) {
    const float* in = (const float*)d_in[0];
    float* out = (float*)d_out;
    dim3 grid(IMG_W / TSX, IMG_H / TSY);
    bilateral_kernel<<<grid, 256, 0, stream>>>(in, out);
}

// Round 7
// 257.177 us; speedup vs baseline: 1.9148x; 1.7648x over previous
//
#include <hip/hip_runtime.h>

#define IMG_H 4096
#define IMG_W 4096
#define RAD 4
#define TSX 64
#define TSY 16
#define LROWS (TSY + 2*RAD)   // 24
#define LCOLS (TSX + 2*RAD)   // 72  (stride 72 floats = 288B; wave b128 reads cover
                              //  4 rows x 64 consecutive floats = every bank exactly 8x = conflict-free)

__device__ __forceinline__ int reflect_idx(int i, int n) {
    i = (i < 0) ? -i : i;
    i = (i >= n) ? (2 * n - 2 - i) : i;
    return i;
}

__global__ __launch_bounds__(256, 8) void bilateral_kernel(const float* __restrict__ in,
                                                           float* __restrict__ out) {
    __shared__ float tile[LROWS * LCOLS];   // 1728 floats = 6912 B
    const int bx = blockIdx.x * TSX;
    const int by = blockIdx.y * TSY;
    const int tid = threadIdx.x;

    const bool interior = (blockIdx.x > 0) && (blockIdx.x < (int)gridDim.x - 1) &&
                          (blockIdx.y > 0) && (blockIdx.y < (int)gridDim.y - 1);
    if (interior) {
        // Fast staging: 24 rows x 18 float4 = 432 coalesced 16B loads, no reflect math.
        const float* src = in + (size_t)(by - RAD) * IMG_W + (bx - RAD);
#pragma unroll
        for (int it = 0; it < 2; ++it) {
            int i = tid + it * 256;
            if (i < 432) {
                int row = i / 18;
                int col = i - row * 18;
                float4 q = *reinterpret_cast<const float4*>(src + row * IMG_W + col * 4);
                *reinterpret_cast<float4*>(&tile[row * 72 + col * 4]) = q;
            }
        }
    } else {
        for (int i = tid; i < LROWS * LCOLS; i += 256) {
            int ly = i / 72;
            int lx = i - ly * 72;
            int gy = reflect_idx(by + ly - RAD, IMG_H);
            int gx = reflect_idx(bx + lx - RAD, IMG_W);
            tile[ly * 72 + lx] = in[gy * IMG_W + gx];
        }
    }
    __syncthreads();

    // 256 threads = 16 tx (4 px wide) x 16 ty (1 px row) -> 64x16 outputs/block.
    const int tx = tid & 15;
    const int ty = tid >> 4;
    const int x0 = tx * 4;

    constexpr float LOG2E  = 1.4426950408889634f;
    constexpr float KR     = -50.0f * LOG2E;        // -log2e/(2*sigma_r^2)
    constexpr float S23    = 8388608.0f;            // 2^23
    constexpr float KRS    = KR * S23;              // KR pre-scaled for Schraudolph
    constexpr float NEG2KRS = -2.0f * KRS;
    constexpr float SC_COEF = -LOG2E / 18.0f;       // -log2e/(2*sigma_s^2)
    constexpr float BIAS   = (127.0f - 0.04303f) * S23;  // centered Schraudolph bias

    // Per-pixel linear coefficient B' = -2*KR'*c. (Dropped KR*c^2 term is a per-pixel
    // constant factor on every weight of that pixel -> cancels in num/den.)
    float B[4];
    {
        float4 c4 = *reinterpret_cast<const float4*>(&tile[(ty + RAD) * 72 + x0 + RAD]);
        B[0] = NEG2KRS * c4.x;
        B[1] = NEG2KRS * c4.y;
        B[2] = NEG2KRS * c4.z;
        B[3] = NEG2KRS * c4.w;
    }

    float n[4] = {0.f, 0.f, 0.f, 0.f};
    float d[4] = {0.f, 0.f, 0.f, 0.f};
    const float* rowp = &tile[ty * 72 + x0];

#pragma unroll 1
    for (int dy = 0; dy < 9; ++dy) {
        float4 q0 = *reinterpret_cast<const float4*>(rowp);
        float4 q1 = *reinterpret_cast<const float4*>(rowp + 4);
        float4 q2 = *reinterpret_cast<const float4*>(rowp + 8);
        rowp += 72;
        float v[12] = {q0.x, q0.y, q0.z, q0.w,
                       q1.x, q1.y, q1.z, q1.w,
                       q2.x, q2.y, q2.z, q2.w};

        // Spatial row factor 2^(SC_COEF*(dy-4)^2), applied to row partials (exact exp).
        int e = dy - 4;
        float fy = __builtin_amdgcn_exp2f(SC_COEF * (float)(e * e));

        float rn[4], rd[4];
#pragma unroll
        for (int dx = 0; dx < 9; ++dx) {
            const int dd = (dx - 4) * (dx - 4);
            const float scb = (float)dd * (SC_COEF * S23) + BIAS;  // compile-time
#pragma unroll
            for (int p = 0; p < 4; ++p) {
                float vv = v[dx + p];
                float t  = fmaf(KRS, vv, B[p]);
                float aa = fmaf(vv, t, scb);        // 2^23*(range-exponent + 126.957)
                float w  = __int_as_float((int)aa); // Schraudolph exp2, +/-3% rel
                if (dx == 0) { rn[p] = w * vv; rd[p] = w; }
                else         { rn[p] = fmaf(w, vv, rn[p]); rd[p] += w; }
            }
        }
#pragma unroll
        for (int p = 0; p < 4; ++p) {
            n[p] = fmaf(fy, rn[p], n[p]);
            d[p] = fmaf(fy, rd[p], d[p]);
        }
    }

    float4 o;
    o.x = n[0] * __builtin_amdgcn_rcpf(d[0]);
    o.y = n[1] * __builtin_amdgcn_rcpf(d[1]);
    o.z = n[2] * __builtin_amdgcn_rcpf(d[2]);
    o.w = n[3] * __builtin_amdgcn_rcpf(d[3]);
    *reinterpret_cast<float4*>(&out[(size_t)(by + ty) * IMG_W + bx + x0]) = o;
}

extern "C" void kernel_launch(void* const* d_in, const int* in_sizes, int n_in,
                              void* d_out, int out_size, void* d_ws, size_t ws_size,
                              hipStream_t stream) {
    const float* in = (const float*)d_in[0];
    float* out = (float*)d_out;
    dim3 grid(IMG_W / TSX, IMG_H / TSY);
    bilateral_kernel<<<grid, 256, 0, stream>>>(in, out);
}